// Round 3
// baseline (117.923 us; speedup 1.0000x reference)
//
#include <hip/hip_runtime.h>
#include <hip/hip_bf16.h>

#define COEFF 1.0f
#define MAX_COLORS 64

// d^2 = |p|^2 + fma(px,-2cx, fma(py,-2cy, fma(pz,-2cz, |c|^2)))
// LDS col[j] = (-2cx, -2cy, -2cz, |c|^2); inner loop = 3 FMA + min per color.
// Single fused kernel: last block (via zeroed counter in d_ws) reduces the
// per-block partials and writes d_out. Counter is hipMemsetAsync'd to 0 at
// the start of every kernel_launch -> identical behavior every call.

template <int MM>
__global__ __launch_bounds__(256) void nps_fused_kernel(
    const float* __restrict__ adv,
    const float* __restrict__ colors,
    float* __restrict__ partials,        // d_ws + 256B
    unsigned int* __restrict__ counter,  // d_ws + 0 (memset to 0 each call)
    float* __restrict__ out,
    int nquads, int npix, int Mrt, float invN)
{
    const int M = (MM > 0) ? MM : Mrt;
    __shared__ float4 col[MAX_COLORS];
    if ((int)threadIdx.x < M) {
        float cx = colors[3 * threadIdx.x + 0];
        float cy = colors[3 * threadIdx.x + 1];
        float cz = colors[3 * threadIdx.x + 2];
        float cc = cx * cx + cy * cy + cz * cz;
        col[threadIdx.x] = make_float4(-2.f * cx, -2.f * cy, -2.f * cz, cc);
    }
    __syncthreads();

    const float4* __restrict__ in4 = (const float4*)adv;
    float lsum = 0.f;
    int tid = blockIdx.x * blockDim.x + threadIdx.x;
    int stride = gridDim.x * blockDim.x;

    for (int q = tid; q < nquads; q += stride) {
        float4 a = in4[3 * q + 0];
        float4 b = in4[3 * q + 1];
        float4 c = in4[3 * q + 2];
        // 12 floats = 4 pixel triples (memory order == reshape(-1,3))
        float px0 = a.x, py0 = a.y, pz0 = a.z;
        float px1 = a.w, py1 = b.x, pz1 = b.y;
        float px2 = b.z, py2 = b.w, pz2 = c.x;
        float px3 = c.y, py3 = c.z, pz3 = c.w;

        float pp0 = fmaf(px0, px0, fmaf(py0, py0, pz0 * pz0));
        float pp1 = fmaf(px1, px1, fmaf(py1, py1, pz1 * pz1));
        float pp2 = fmaf(px2, px2, fmaf(py2, py2, pz2 * pz2));
        float pp3 = fmaf(px3, px3, fmaf(py3, py3, pz3 * pz3));

        float mn0 = 3.4e38f, mn1 = 3.4e38f, mn2 = 3.4e38f, mn3 = 3.4e38f;

        // groups of 3 colors -> fminf(fminf(t0,t1),t2) fuses to v_min3_f32
        #pragma unroll
        for (int j = 0; j + 2 < M; j += 3) {
            float4 c0 = col[j], c1 = col[j + 1], c2 = col[j + 2];
            float t0, t1, t2;
            t0 = fmaf(px0, c0.x, fmaf(py0, c0.y, fmaf(pz0, c0.z, c0.w)));
            t1 = fmaf(px0, c1.x, fmaf(py0, c1.y, fmaf(pz0, c1.z, c1.w)));
            t2 = fmaf(px0, c2.x, fmaf(py0, c2.y, fmaf(pz0, c2.z, c2.w)));
            mn0 = fminf(mn0, fminf(fminf(t0, t1), t2));
            t0 = fmaf(px1, c0.x, fmaf(py1, c0.y, fmaf(pz1, c0.z, c0.w)));
            t1 = fmaf(px1, c1.x, fmaf(py1, c1.y, fmaf(pz1, c1.z, c1.w)));
            t2 = fmaf(px1, c2.x, fmaf(py1, c2.y, fmaf(pz1, c2.z, c2.w)));
            mn1 = fminf(mn1, fminf(fminf(t0, t1), t2));
            t0 = fmaf(px2, c0.x, fmaf(py2, c0.y, fmaf(pz2, c0.z, c0.w)));
            t1 = fmaf(px2, c1.x, fmaf(py2, c1.y, fmaf(pz2, c1.z, c1.w)));
            t2 = fmaf(px2, c2.x, fmaf(py2, c2.y, fmaf(pz2, c2.z, c2.w)));
            mn2 = fminf(mn2, fminf(fminf(t0, t1), t2));
            t0 = fmaf(px3, c0.x, fmaf(py3, c0.y, fmaf(pz3, c0.z, c0.w)));
            t1 = fmaf(px3, c1.x, fmaf(py3, c1.y, fmaf(pz3, c1.z, c1.w)));
            t2 = fmaf(px3, c2.x, fmaf(py3, c2.y, fmaf(pz3, c2.z, c2.w)));
            mn3 = fminf(mn3, fminf(fminf(t0, t1), t2));
        }
        #pragma unroll
        for (int j = M - (M % 3); j < M; ++j) {
            float4 cj = col[j];
            mn0 = fminf(mn0, fmaf(px0, cj.x, fmaf(py0, cj.y, fmaf(pz0, cj.z, cj.w))));
            mn1 = fminf(mn1, fmaf(px1, cj.x, fmaf(py1, cj.y, fmaf(pz1, cj.z, cj.w))));
            mn2 = fminf(mn2, fmaf(px2, cj.x, fmaf(py2, cj.y, fmaf(pz2, cj.z, cj.w))));
            mn3 = fminf(mn3, fmaf(px3, cj.x, fmaf(py3, cj.y, fmaf(pz3, cj.z, cj.w))));
        }
        lsum += sqrtf(fmaxf(pp0 + mn0, 0.f)) + sqrtf(fmaxf(pp1 + mn1, 0.f))
              + sqrtf(fmaxf(pp2 + mn2, 0.f)) + sqrtf(fmaxf(pp3 + mn3, 0.f));
    }

    // tail pixels (npix % 4 != 0) — zero iterations at this problem size
    if (tid == 0) {
        for (int p = nquads * 4; p < npix; ++p) {
            float px = adv[3 * p], py = adv[3 * p + 1], pz = adv[3 * p + 2];
            float pp = fmaf(px, px, fmaf(py, py, pz * pz));
            float mn = 3.4e38f;
            for (int j = 0; j < M; ++j) {
                float4 cj = col[j];
                mn = fminf(mn, fmaf(px, cj.x, fmaf(py, cj.y, fmaf(pz, cj.z, cj.w))));
            }
            lsum += sqrtf(fmaxf(pp + mn, 0.f));
        }
    }

    // block reduction
    #pragma unroll
    for (int off = 32; off > 0; off >>= 1) lsum += __shfl_down(lsum, off, 64);
    __shared__ float wsum[4];
    int lane = threadIdx.x & 63, wid = threadIdx.x >> 6;
    if (lane == 0) wsum[wid] = lsum;
    __syncthreads();

    // publish partial, then last-arriving block folds all partials into out
    __shared__ bool amLast;
    if (threadIdx.x == 0) {
        partials[blockIdx.x] = wsum[0] + wsum[1] + wsum[2] + wsum[3];
        __threadfence();  // make partial visible device-wide before arrival
        unsigned int old = atomicAdd(counter, 1u);
        amLast = (old == gridDim.x - 1);
    }
    __syncthreads();

    if (amLast) {
        __threadfence();  // acquire: see all partials
        float s = 0.f;
        for (int i = threadIdx.x; i < (int)gridDim.x; i += 256)
            s += partials[i];
        #pragma unroll
        for (int off = 32; off > 0; off >>= 1) s += __shfl_down(s, off, 64);
        if (lane == 0) wsum[wid] = s;
        __syncthreads();
        if (threadIdx.x == 0)
            out[0] = (wsum[0] + wsum[1] + wsum[2] + wsum[3]) * invN * COEFF;
    }
}

extern "C" void kernel_launch(void* const* d_in, const int* in_sizes, int n_in,
                              void* d_out, int out_size, void* d_ws, size_t ws_size,
                              hipStream_t stream) {
    const float* adv    = (const float*)d_in[0];
    const float* colors = (const float*)d_in[1];
    float* out = (float*)d_out;

    int npix   = in_sizes[0] / 3;      // 2,097,152
    int M      = in_sizes[1] / 3;      // 30
    int nquads = npix / 4;             // 524,288 (exact)

    int blocks = (nquads + 255) / 256;
    if (blocks > 2048) blocks = 2048;  // 8 blocks/CU -> full occupancy

    unsigned int* counter = (unsigned int*)d_ws;          // 4B, zeroed below
    float* partials = (float*)((char*)d_ws + 256);        // blocks floats

    hipMemsetAsync(counter, 0, sizeof(unsigned int), stream);  // graph-safe node

    if (M == 30) {
        nps_fused_kernel<30><<<blocks, 256, 0, stream>>>(
            adv, colors, partials, counter, out, nquads, npix, M,
            1.0f / (float)npix);
    } else if (M <= MAX_COLORS) {
        nps_fused_kernel<0><<<blocks, 256, 0, stream>>>(
            adv, colors, partials, counter, out, nquads, npix, M,
            1.0f / (float)npix);
    }
}

// Round 4
// 93.855 us; speedup vs baseline: 1.2564x; 1.2564x over previous
//
#include <hip/hip_runtime.h>
#include <hip/hip_bf16.h>

#define COEFF 1.0f
#define MAX_COLORS 64

// d^2 = |p|^2 + fma(px,-2cx, fma(py,-2cy, fma(pz,-2cz, |c|^2)))
// LDS col[j] = (-2cx, -2cy, -2cz, |c|^2); inner loop = 3 FMA + min per color.
// Single kernel, NO fences: each block atomicAdd's its scaled partial into
// out[0] (device-scope atomic, no L2 writeback -- the R3 fence regression).
// out[0] is zeroed by a 4-byte hipMemsetAsync graph node each call.

template <int MM>
__global__ __launch_bounds__(256) void nps_atomic_kernel(
    const float* __restrict__ adv,
    const float* __restrict__ colors,
    float* __restrict__ out,
    int nquads, int npix, int Mrt, float invN)
{
    const int M = (MM > 0) ? MM : Mrt;
    __shared__ float4 col[MAX_COLORS];
    if ((int)threadIdx.x < M) {
        float cx = colors[3 * threadIdx.x + 0];
        float cy = colors[3 * threadIdx.x + 1];
        float cz = colors[3 * threadIdx.x + 2];
        float cc = cx * cx + cy * cy + cz * cz;
        col[threadIdx.x] = make_float4(-2.f * cx, -2.f * cy, -2.f * cz, cc);
    }
    __syncthreads();

    const float4* __restrict__ in4 = (const float4*)adv;
    float lsum = 0.f;
    int tid = blockIdx.x * blockDim.x + threadIdx.x;
    int stride = gridDim.x * blockDim.x;

    for (int q = tid; q < nquads; q += stride) {
        float4 a = in4[3 * q + 0];
        float4 b = in4[3 * q + 1];
        float4 c = in4[3 * q + 2];
        // 12 floats = 4 pixel triples (memory order == reshape(-1,3))
        float px0 = a.x, py0 = a.y, pz0 = a.z;
        float px1 = a.w, py1 = b.x, pz1 = b.y;
        float px2 = b.z, py2 = b.w, pz2 = c.x;
        float px3 = c.y, py3 = c.z, pz3 = c.w;

        float pp0 = fmaf(px0, px0, fmaf(py0, py0, pz0 * pz0));
        float pp1 = fmaf(px1, px1, fmaf(py1, py1, pz1 * pz1));
        float pp2 = fmaf(px2, px2, fmaf(py2, py2, pz2 * pz2));
        float pp3 = fmaf(px3, px3, fmaf(py3, py3, pz3 * pz3));

        float mn0 = 3.4e38f, mn1 = 3.4e38f, mn2 = 3.4e38f, mn3 = 3.4e38f;

        // groups of 3 colors -> fminf(fminf(t0,t1),t2) fuses to v_min3_f32
        #pragma unroll
        for (int j = 0; j + 2 < M; j += 3) {
            float4 c0 = col[j], c1 = col[j + 1], c2 = col[j + 2];
            float t0, t1, t2;
            t0 = fmaf(px0, c0.x, fmaf(py0, c0.y, fmaf(pz0, c0.z, c0.w)));
            t1 = fmaf(px0, c1.x, fmaf(py0, c1.y, fmaf(pz0, c1.z, c1.w)));
            t2 = fmaf(px0, c2.x, fmaf(py0, c2.y, fmaf(pz0, c2.z, c2.w)));
            mn0 = fminf(mn0, fminf(fminf(t0, t1), t2));
            t0 = fmaf(px1, c0.x, fmaf(py1, c0.y, fmaf(pz1, c0.z, c0.w)));
            t1 = fmaf(px1, c1.x, fmaf(py1, c1.y, fmaf(pz1, c1.z, c1.w)));
            t2 = fmaf(px1, c2.x, fmaf(py1, c2.y, fmaf(pz1, c2.z, c2.w)));
            mn1 = fminf(mn1, fminf(fminf(t0, t1), t2));
            t0 = fmaf(px2, c0.x, fmaf(py2, c0.y, fmaf(pz2, c0.z, c0.w)));
            t1 = fmaf(px2, c1.x, fmaf(py2, c1.y, fmaf(pz2, c1.z, c1.w)));
            t2 = fmaf(px2, c2.x, fmaf(py2, c2.y, fmaf(pz2, c2.z, c2.w)));
            mn2 = fminf(mn2, fminf(fminf(t0, t1), t2));
            t0 = fmaf(px3, c0.x, fmaf(py3, c0.y, fmaf(pz3, c0.z, c0.w)));
            t1 = fmaf(px3, c1.x, fmaf(py3, c1.y, fmaf(pz3, c1.z, c1.w)));
            t2 = fmaf(px3, c2.x, fmaf(py3, c2.y, fmaf(pz3, c2.z, c2.w)));
            mn3 = fminf(mn3, fminf(fminf(t0, t1), t2));
        }
        #pragma unroll
        for (int j = M - (M % 3); j < M; ++j) {
            float4 cj = col[j];
            mn0 = fminf(mn0, fmaf(px0, cj.x, fmaf(py0, cj.y, fmaf(pz0, cj.z, cj.w))));
            mn1 = fminf(mn1, fmaf(px1, cj.x, fmaf(py1, cj.y, fmaf(pz1, cj.z, cj.w))));
            mn2 = fminf(mn2, fmaf(px2, cj.x, fmaf(py2, cj.y, fmaf(pz2, cj.z, cj.w))));
            mn3 = fminf(mn3, fmaf(px3, cj.x, fmaf(py3, cj.y, fmaf(pz3, cj.z, cj.w))));
        }
        lsum += sqrtf(fmaxf(pp0 + mn0, 0.f)) + sqrtf(fmaxf(pp1 + mn1, 0.f))
              + sqrtf(fmaxf(pp2 + mn2, 0.f)) + sqrtf(fmaxf(pp3 + mn3, 0.f));
    }

    // tail pixels (npix % 4 != 0) — zero iterations at this problem size
    if (tid == 0) {
        for (int p = nquads * 4; p < npix; ++p) {
            float px = adv[3 * p], py = adv[3 * p + 1], pz = adv[3 * p + 2];
            float pp = fmaf(px, px, fmaf(py, py, pz * pz));
            float mn = 3.4e38f;
            for (int j = 0; j < M; ++j) {
                float4 cj = col[j];
                mn = fminf(mn, fmaf(px, cj.x, fmaf(py, cj.y, fmaf(pz, cj.z, cj.w))));
            }
            lsum += sqrtf(fmaxf(pp + mn, 0.f));
        }
    }

    // block reduction, then ONE device-scope float atomic per block (no fence)
    #pragma unroll
    for (int off = 32; off > 0; off >>= 1) lsum += __shfl_down(lsum, off, 64);
    __shared__ float wsum[4];
    int lane = threadIdx.x & 63, wid = threadIdx.x >> 6;
    if (lane == 0) wsum[wid] = lsum;
    __syncthreads();
    if (threadIdx.x == 0)
        atomicAdd(out, (wsum[0] + wsum[1] + wsum[2] + wsum[3]) * invN * COEFF);
}

extern "C" void kernel_launch(void* const* d_in, const int* in_sizes, int n_in,
                              void* d_out, int out_size, void* d_ws, size_t ws_size,
                              hipStream_t stream) {
    const float* adv    = (const float*)d_in[0];
    const float* colors = (const float*)d_in[1];
    float* out = (float*)d_out;

    int npix   = in_sizes[0] / 3;      // 2,097,152
    int M      = in_sizes[1] / 3;      // 30
    int nquads = npix / 4;             // 524,288 (exact)

    int blocks = (nquads + 255) / 256;
    if (blocks > 2048) blocks = 2048;  // 8 blocks/CU

    hipMemsetAsync(out, 0, sizeof(float), stream);  // graph-safe 4B node

    if (M == 30) {
        nps_atomic_kernel<30><<<blocks, 256, 0, stream>>>(
            adv, colors, out, nquads, npix, M, 1.0f / (float)npix);
    } else if (M <= MAX_COLORS) {
        nps_atomic_kernel<0><<<blocks, 256, 0, stream>>>(
            adv, colors, out, nquads, npix, M, 1.0f / (float)npix);
    }
}

// Round 5
// 77.969 us; speedup vs baseline: 1.5124x; 1.2037x over previous
//
#include <hip/hip_runtime.h>
#include <hip/hip_bf16.h>

#define COEFF 1.0f
#define MAX_COLORS 64

// d^2 = |p|^2 + fma(px,-2cx, fma(py,-2cy, fma(pz,-2cz, |c|^2)))
// LDS col[j] = (-2cx,-2cy,-2cz,|c|^2); 3 FMA + min per color per pixel,
// grouped x3 so clang emits v_min3_f32.
// Two-kernel deterministic reduction (R2 structure = best at 78.6us;
// fences +39us, same-address atomics +14us -- both rejected).
// This round: 2 quads/thread (8 independent min-chains, 6 loads up-front)
// to attack latency-boundedness of the partial kernel.

template <int MM>
__global__ __launch_bounds__(256) void nps_partial_kernel(
    const float* __restrict__ adv,
    const float* __restrict__ colors,
    float* __restrict__ partials,
    int nquads, int npix, int Mrt)
{
    const int M = (MM > 0) ? MM : Mrt;
    __shared__ float4 col[MAX_COLORS];
    if ((int)threadIdx.x < M) {
        float cx = colors[3 * threadIdx.x + 0];
        float cy = colors[3 * threadIdx.x + 1];
        float cz = colors[3 * threadIdx.x + 2];
        float cc = cx * cx + cy * cy + cz * cz;
        col[threadIdx.x] = make_float4(-2.f * cx, -2.f * cy, -2.f * cz, cc);
    }
    __syncthreads();

    const float4* __restrict__ in4 = (const float4*)adv;
    float lsum = 0.f;
    int tid = blockIdx.x * blockDim.x + threadIdx.x;
    int stride = gridDim.x * blockDim.x;   // 262144 at this config

    for (int q = tid; q < nquads; q += 2 * stride) {
        int q2 = q + stride;
        bool has2 = (q2 < nquads);         // uniformly true at this config

        // issue all loads up-front (independent chains -> overlap latency)
        float4 a0 = in4[3 * q + 0];
        float4 b0 = in4[3 * q + 1];
        float4 c0 = in4[3 * q + 2];
        float4 a1, b1, c1;
        if (has2) {
            a1 = in4[3 * q2 + 0];
            b1 = in4[3 * q2 + 1];
            c1 = in4[3 * q2 + 2];
        } else {
            a1 = make_float4(0.f, 0.f, 0.f, 0.f);
            b1 = a1; c1 = a1;
        }

        // 12 floats = 4 pixel triples (memory order == reshape(-1,3))
        float px0 = a0.x, py0 = a0.y, pz0 = a0.z;
        float px1 = a0.w, py1 = b0.x, pz1 = b0.y;
        float px2 = b0.z, py2 = b0.w, pz2 = c0.x;
        float px3 = c0.y, py3 = c0.z, pz3 = c0.w;
        float px4 = a1.x, py4 = a1.y, pz4 = a1.z;
        float px5 = a1.w, py5 = b1.x, pz5 = b1.y;
        float px6 = b1.z, py6 = b1.w, pz6 = c1.x;
        float px7 = c1.y, py7 = c1.z, pz7 = c1.w;

        float pp0 = fmaf(px0, px0, fmaf(py0, py0, pz0 * pz0));
        float pp1 = fmaf(px1, px1, fmaf(py1, py1, pz1 * pz1));
        float pp2 = fmaf(px2, px2, fmaf(py2, py2, pz2 * pz2));
        float pp3 = fmaf(px3, px3, fmaf(py3, py3, pz3 * pz3));
        float pp4 = fmaf(px4, px4, fmaf(py4, py4, pz4 * pz4));
        float pp5 = fmaf(px5, px5, fmaf(py5, py5, pz5 * pz5));
        float pp6 = fmaf(px6, px6, fmaf(py6, py6, pz6 * pz6));
        float pp7 = fmaf(px7, px7, fmaf(py7, py7, pz7 * pz7));

        float mn0 = 3.4e38f, mn1 = 3.4e38f, mn2 = 3.4e38f, mn3 = 3.4e38f;
        float mn4 = 3.4e38f, mn5 = 3.4e38f, mn6 = 3.4e38f, mn7 = 3.4e38f;

        #pragma unroll
        for (int j = 0; j + 2 < M; j += 3) {
            float4 c0v = col[j], c1v = col[j + 1], c2v = col[j + 2];
            float t0, t1, t2;
            t0 = fmaf(px0, c0v.x, fmaf(py0, c0v.y, fmaf(pz0, c0v.z, c0v.w)));
            t1 = fmaf(px0, c1v.x, fmaf(py0, c1v.y, fmaf(pz0, c1v.z, c1v.w)));
            t2 = fmaf(px0, c2v.x, fmaf(py0, c2v.y, fmaf(pz0, c2v.z, c2v.w)));
            mn0 = fminf(mn0, fminf(fminf(t0, t1), t2));
            t0 = fmaf(px1, c0v.x, fmaf(py1, c0v.y, fmaf(pz1, c0v.z, c0v.w)));
            t1 = fmaf(px1, c1v.x, fmaf(py1, c1v.y, fmaf(pz1, c1v.z, c1v.w)));
            t2 = fmaf(px1, c2v.x, fmaf(py1, c2v.y, fmaf(pz1, c2v.z, c2v.w)));
            mn1 = fminf(mn1, fminf(fminf(t0, t1), t2));
            t0 = fmaf(px2, c0v.x, fmaf(py2, c0v.y, fmaf(pz2, c0v.z, c0v.w)));
            t1 = fmaf(px2, c1v.x, fmaf(py2, c1v.y, fmaf(pz2, c1v.z, c1v.w)));
            t2 = fmaf(px2, c2v.x, fmaf(py2, c2v.y, fmaf(pz2, c2v.z, c2v.w)));
            mn2 = fminf(mn2, fminf(fminf(t0, t1), t2));
            t0 = fmaf(px3, c0v.x, fmaf(py3, c0v.y, fmaf(pz3, c0v.z, c0v.w)));
            t1 = fmaf(px3, c1v.x, fmaf(py3, c1v.y, fmaf(pz3, c1v.z, c1v.w)));
            t2 = fmaf(px3, c2v.x, fmaf(py3, c2v.y, fmaf(pz3, c2v.z, c2v.w)));
            mn3 = fminf(mn3, fminf(fminf(t0, t1), t2));
            t0 = fmaf(px4, c0v.x, fmaf(py4, c0v.y, fmaf(pz4, c0v.z, c0v.w)));
            t1 = fmaf(px4, c1v.x, fmaf(py4, c1v.y, fmaf(pz4, c1v.z, c1v.w)));
            t2 = fmaf(px4, c2v.x, fmaf(py4, c2v.y, fmaf(pz4, c2v.z, c2v.w)));
            mn4 = fminf(mn4, fminf(fminf(t0, t1), t2));
            t0 = fmaf(px5, c0v.x, fmaf(py5, c0v.y, fmaf(pz5, c0v.z, c0v.w)));
            t1 = fmaf(px5, c1v.x, fmaf(py5, c1v.y, fmaf(pz5, c1v.z, c1v.w)));
            t2 = fmaf(px5, c2v.x, fmaf(py5, c2v.y, fmaf(pz5, c2v.z, c2v.w)));
            mn5 = fminf(mn5, fminf(fminf(t0, t1), t2));
            t0 = fmaf(px6, c0v.x, fmaf(py6, c0v.y, fmaf(pz6, c0v.z, c0v.w)));
            t1 = fmaf(px6, c1v.x, fmaf(py6, c1v.y, fmaf(pz6, c1v.z, c1v.w)));
            t2 = fmaf(px6, c2v.x, fmaf(py6, c2v.y, fmaf(pz6, c2v.z, c2v.w)));
            mn6 = fminf(mn6, fminf(fminf(t0, t1), t2));
            t0 = fmaf(px7, c0v.x, fmaf(py7, c0v.y, fmaf(pz7, c0v.z, c0v.w)));
            t1 = fmaf(px7, c1v.x, fmaf(py7, c1v.y, fmaf(pz7, c1v.z, c1v.w)));
            t2 = fmaf(px7, c2v.x, fmaf(py7, c2v.y, fmaf(pz7, c2v.z, c2v.w)));
            mn7 = fminf(mn7, fminf(fminf(t0, t1), t2));
        }
        #pragma unroll
        for (int j = M - (M % 3); j < M; ++j) {
            float4 cj = col[j];
            mn0 = fminf(mn0, fmaf(px0, cj.x, fmaf(py0, cj.y, fmaf(pz0, cj.z, cj.w))));
            mn1 = fminf(mn1, fmaf(px1, cj.x, fmaf(py1, cj.y, fmaf(pz1, cj.z, cj.w))));
            mn2 = fminf(mn2, fmaf(px2, cj.x, fmaf(py2, cj.y, fmaf(pz2, cj.z, cj.w))));
            mn3 = fminf(mn3, fmaf(px3, cj.x, fmaf(py3, cj.y, fmaf(pz3, cj.z, cj.w))));
            mn4 = fminf(mn4, fmaf(px4, cj.x, fmaf(py4, cj.y, fmaf(pz4, cj.z, cj.w))));
            mn5 = fminf(mn5, fmaf(px5, cj.x, fmaf(py5, cj.y, fmaf(pz5, cj.z, cj.w))));
            mn6 = fminf(mn6, fmaf(px6, cj.x, fmaf(py6, cj.y, fmaf(pz6, cj.z, cj.w))));
            mn7 = fminf(mn7, fmaf(px7, cj.x, fmaf(py7, cj.y, fmaf(pz7, cj.z, cj.w))));
        }

        float s0 = sqrtf(fmaxf(pp0 + mn0, 0.f)) + sqrtf(fmaxf(pp1 + mn1, 0.f))
                 + sqrtf(fmaxf(pp2 + mn2, 0.f)) + sqrtf(fmaxf(pp3 + mn3, 0.f));
        float s1 = sqrtf(fmaxf(pp4 + mn4, 0.f)) + sqrtf(fmaxf(pp5 + mn5, 0.f))
                 + sqrtf(fmaxf(pp6 + mn6, 0.f)) + sqrtf(fmaxf(pp7 + mn7, 0.f));
        lsum += s0 + (has2 ? s1 : 0.f);
    }

    // tail pixels (npix % 4 != 0) — zero iterations at this problem size
    if (tid == 0) {
        for (int p = nquads * 4; p < npix; ++p) {
            float px = adv[3 * p], py = adv[3 * p + 1], pz = adv[3 * p + 2];
            float pp = fmaf(px, px, fmaf(py, py, pz * pz));
            float mn = 3.4e38f;
            for (int j = 0; j < M; ++j) {
                float4 cj = col[j];
                mn = fminf(mn, fmaf(px, cj.x, fmaf(py, cj.y, fmaf(pz, cj.z, cj.w))));
            }
            lsum += sqrtf(fmaxf(pp + mn, 0.f));
        }
    }

    // wave64 reduce, then cross-wave via LDS
    #pragma unroll
    for (int off = 32; off > 0; off >>= 1) lsum += __shfl_down(lsum, off, 64);
    __shared__ float wsum[4];
    int lane = threadIdx.x & 63, wid = threadIdx.x >> 6;
    if (lane == 0) wsum[wid] = lsum;
    __syncthreads();
    if (threadIdx.x == 0)
        partials[blockIdx.x] = wsum[0] + wsum[1] + wsum[2] + wsum[3];
}

__global__ __launch_bounds__(256) void nps_final_kernel(
    const float* __restrict__ partials, int nparts,
    float* __restrict__ out, float invN)
{
    float s = 0.f;
    for (int i = threadIdx.x; i < nparts; i += 256) s += partials[i];
    #pragma unroll
    for (int off = 32; off > 0; off >>= 1) s += __shfl_down(s, off, 64);
    __shared__ float wsum[4];
    int lane = threadIdx.x & 63, wid = threadIdx.x >> 6;
    if (lane == 0) wsum[wid] = s;
    __syncthreads();
    if (threadIdx.x == 0)
        out[0] = (wsum[0] + wsum[1] + wsum[2] + wsum[3]) * invN * COEFF;
}

extern "C" void kernel_launch(void* const* d_in, const int* in_sizes, int n_in,
                              void* d_out, int out_size, void* d_ws, size_t ws_size,
                              hipStream_t stream) {
    const float* adv    = (const float*)d_in[0];
    const float* colors = (const float*)d_in[1];
    float* out = (float*)d_out;

    int npix   = in_sizes[0] / 3;      // 2,097,152
    int M      = in_sizes[1] / 3;      // 30
    int nquads = npix / 4;             // 524,288 (exact)

    // 2 quads per thread -> half the blocks of R2
    int blocks = (nquads + 511) / 512;
    if (blocks > 1024) blocks = 1024;  // 1024 * 256 * 2 = 524288 quads exactly

    float* partials = (float*)d_ws;    // blocks floats; every slot written

    if (M == 30) {
        nps_partial_kernel<30><<<blocks, 256, 0, stream>>>(adv, colors, partials,
                                                           nquads, npix, M);
    } else if (M <= MAX_COLORS) {
        nps_partial_kernel<0><<<blocks, 256, 0, stream>>>(adv, colors, partials,
                                                          nquads, npix, M);
    }
    nps_final_kernel<<<1, 256, 0, stream>>>(partials, blocks, out,
                                            1.0f / (float)npix);
}